// Round 1
// baseline (145.508 us; speedup 1.0000x reference)
//
#include <hip/hip_runtime.h>

#define H 1024
#define W 1024
#define BATCH 16
#define TX 64
#define TY 32
#define TGW (TX + 4)   // 68: targets tile width (halo 2)
#define TGH (TY + 4)   // 36
#define TEW (TX + 2)   // 66: inputs / target-edge tile width (halo 1)
#define TEH (TY + 2)   // 34
#define NTHREADS 256

__global__ __launch_bounds__(NTHREADS) void edge_loss_main(
    const float* __restrict__ inp, const float* __restrict__ tgt,
    double* __restrict__ acc)
{
    __shared__ float sT[TGH * TGW];   // targets, halo 2
    __shared__ float sI[TEH * TEW];   // inputs, halo 1
    __shared__ float sE[TEH * TEW];   // target edge, halo 1

    const int b   = blockIdx.z;
    const int ty0 = blockIdx.y * TY;
    const int tx0 = blockIdx.x * TX;
    const float* __restrict__ inB = inp + (size_t)b * (H * W);
    const float* __restrict__ tgB = tgt + (size_t)b * (H * W);
    const int tid = threadIdx.x;

    // ---- stage targets (halo 2), zero outside image (conv zero-pad) ----
    for (int i = tid; i < TGH * TGW; i += NTHREADS) {
        int r = i / TGW, c = i - r * TGW;
        int gy = ty0 + r - 2, gx = tx0 + c - 2;
        float v = 0.f;
        if ((unsigned)gy < H && (unsigned)gx < W) v = tgB[gy * W + gx];
        sT[i] = v;
    }
    // ---- stage inputs (halo 1) ----
    for (int i = tid; i < TEH * TEW; i += NTHREADS) {
        int r = i / TEW, c = i - r * TEW;
        int gy = ty0 + r - 1, gx = tx0 + c - 1;
        float v = 0.f;
        if ((unsigned)gy < H && (unsigned)gx < W) v = inB[gy * W + gx];
        sI[i] = v;
    }
    __syncthreads();

    // ---- target edge magnitude (halo 1). Outside image -> 0 sentinel:
    // edge >= 0 and the 3x3 maxpool window always contains the valid center,
    // so a 0 sentinel is equivalent to the reference's -inf padding. ----
    for (int i = tid; i < TEH * TEW; i += NTHREADS) {
        int r = i / TEW, c = i - r * TEW;
        int gy = ty0 + r - 1, gx = tx0 + c - 1;
        float e = 0.f;
        if ((unsigned)gy < H && (unsigned)gx < W) {
            const float* p0 = &sT[(r + 0) * TGW + c];
            const float* p1 = &sT[(r + 1) * TGW + c];
            const float* p2 = &sT[(r + 2) * TGW + c];
            float a00 = p0[0], a01 = p0[1], a02 = p0[2];
            float a10 = p1[0],              a12 = p1[2];
            float a20 = p2[0], a21 = p2[1], a22 = p2[2];
            float gxv = (a02 - a00) + 2.f * (a12 - a10) + (a22 - a20);
            float gyv = (a20 - a00) + 2.f * (a21 - a01) + (a22 - a02);
            e = sqrtf(gxv * gxv + gyv * gyv);
        }
        sE[i] = e;
    }
    __syncthreads();

    // ---- per-pixel: pred edge, maxpooled target edge, loss accumulate ----
    float lsum = 0.f;
    for (int i = tid; i < TY * TX; i += NTHREADS) {
        int r = i >> 6, c = i & (TX - 1);     // TX == 64
        const float* q0 = &sI[(r + 0) * TEW + c];
        const float* q1 = &sI[(r + 1) * TEW + c];
        const float* q2 = &sI[(r + 2) * TEW + c];
        float a00 = q0[0], a01 = q0[1], a02 = q0[2];
        float a10 = q1[0],              a12 = q1[2];
        float a20 = q2[0], a21 = q2[1], a22 = q2[2];
        float gxv = (a02 - a00) + 2.f * (a12 - a10) + (a22 - a20);
        float gyv = (a20 - a00) + 2.f * (a21 - a01) + (a22 - a02);
        float pe = sqrtf(gxv * gxv + gyv * gyv);

        const float* e0 = &sE[(r + 0) * TEW + c];
        const float* e1 = &sE[(r + 1) * TEW + c];
        const float* e2 = &sE[(r + 2) * TEW + c];
        float m = fmaxf(fmaxf(fmaxf(e0[0], e0[1]), fmaxf(e0[2], e1[0])),
                        fmaxf(fmaxf(e1[1], e1[2]),
                              fmaxf(fmaxf(e2[0], e2[1]), e2[2])));
        float d = m * (pe - 1.f);   // pe*te - te == te*(pe-1)
        lsum += d * d;
    }

    // ---- reduce: wave64 shuffle -> LDS -> one double atomicAdd per block ----
    for (int off = 32; off > 0; off >>= 1)
        lsum += __shfl_down(lsum, off);
    __shared__ float wsum[NTHREADS / 64];
    const int wave = tid >> 6, lane = tid & 63;
    if (lane == 0) wsum[wave] = lsum;
    __syncthreads();
    if (tid == 0) {
        float bsum = 0.f;
        #pragma unroll
        for (int w2 = 0; w2 < NTHREADS / 64; ++w2) bsum += wsum[w2];
        atomicAdd(acc, (double)bsum);
    }
}

__global__ void edge_loss_finalize(const double* __restrict__ acc,
                                   float* __restrict__ out)
{
    out[0] = (float)(acc[0] / (double)((size_t)BATCH * H * W));
}

extern "C" void kernel_launch(void* const* d_in, const int* in_sizes, int n_in,
                              void* d_out, int out_size, void* d_ws, size_t ws_size,
                              hipStream_t stream)
{
    const float* inputs  = (const float*)d_in[0];
    const float* targets = (const float*)d_in[1];
    float* out  = (float*)d_out;
    double* acc = (double*)d_ws;

    hipMemsetAsync(acc, 0, sizeof(double), stream);
    dim3 grid(W / TX, H / TY, BATCH);
    edge_loss_main<<<grid, NTHREADS, 0, stream>>>(inputs, targets, acc);
    edge_loss_finalize<<<1, 1, 0, stream>>>(acc, out);
}

// Round 2
// 102.557 us; speedup vs baseline: 1.4188x; 1.4188x over previous
//
#include <hip/hip_runtime.h>

#define H 1024
#define W 1024
#define BATCH 16
#define TX 128
#define TY 32
#define FRW 136            // frame width in floats; frame col c <-> gx = tx0-4+c
#define FRH 34             // frame rows; fr <-> gy = ty0-1+fr
#define NT 256
#define GX (W / TX)        // 8
#define GY (H / TY)        // 32
#define EDGE_TASKS (FRH * 17)   // 578 pair-tasks (17 8-wide pairs per frame row)

// ---- guarded loads (G=false compiles to raw vector/scalar loads) ----
template<bool G>
__device__ __forceinline__ float4 ld4(const float* __restrict__ img, int gy, int gx) {
    if (!G) return *(const float4*)(img + gy * W + gx);
    if ((unsigned)gy >= H) return make_float4(0.f, 0.f, 0.f, 0.f);
    const float* row = img + (size_t)gy * W;
    if ((unsigned)gx <= (unsigned)(W - 4)) return *(const float4*)(row + gx);
    float4 v;
    v.x = ((unsigned)(gx + 0) < W) ? row[gx + 0] : 0.f;
    v.y = ((unsigned)(gx + 1) < W) ? row[gx + 1] : 0.f;
    v.z = ((unsigned)(gx + 2) < W) ? row[gx + 2] : 0.f;
    v.w = ((unsigned)(gx + 3) < W) ? row[gx + 3] : 0.f;
    return v;
}

template<bool G>
__device__ __forceinline__ float ld1(const float* __restrict__ img, int gy, int gx) {
    if (!G) return img[gy * W + gx];
    if ((unsigned)gy >= H || (unsigned)gx >= W) return 0.f;
    return img[(size_t)gy * W + gx];
}

// t[0..9] = img[gy][gxb-1 .. gxb+8]  (gxb is 4-aligned when tx0 % 4 == 0)
template<bool G>
__device__ __forceinline__ void loadrow(float t[10], const float* __restrict__ img,
                                        int gy, int gxb) {
    t[0] = ld1<G>(img, gy, gxb - 1);
    float4 m0 = ld4<G>(img, gy, gxb);
    float4 m1 = ld4<G>(img, gy, gxb + 4);
    t[1] = m0.x; t[2] = m0.y; t[3] = m0.z; t[4] = m0.w;
    t[5] = m1.x; t[6] = m1.y; t[7] = m1.z; t[8] = m1.w;
    t[9] = ld1<G>(img, gy, gxb + 8);
}

// 8 Sobel magnitudes from 3 rows of 10 (shared-column factorization)
__device__ __forceinline__ void sobel8(const float a[10], const float b[10],
                                       const float c[10], float e[8]) {
    float t2[10], dz[10];
    #pragma unroll
    for (int k = 0; k < 10; ++k) {
        t2[k] = a[k] + 2.f * b[k] + c[k];   // x-gradient row-combine
        dz[k] = c[k] - a[k];                // y-gradient row-combine
    }
    #pragma unroll
    for (int j = 0; j < 8; ++j) {
        float gxv = t2[j + 2] - t2[j];
        float gyv = dz[j] + 2.f * dz[j + 1] + dz[j + 2];
        e[j] = sqrtf(gxv * gxv + gyv * gyv);
    }
}

// t[0..9] = sE[fr][c0+3 .. c0+12]  (4 aligned float4 reads)
__device__ __forceinline__ void ldsrow(float t[10], const float* __restrict__ sE,
                                       int fr, int c0) {
    const float4* q = (const float4*)&sE[fr * FRW + c0];
    float4 q0 = q[0], q1 = q[1], q2 = q[2], q3 = q[3];
    t[0] = q0.w;
    t[1] = q1.x; t[2] = q1.y; t[3] = q1.z; t[4] = q1.w;
    t[5] = q2.x; t[6] = q2.y; t[7] = q2.z; t[8] = q2.w;
    t[9] = q3.x;
}

template<bool G>
__device__ __forceinline__ float body(const float* __restrict__ inB,
                                      const float* __restrict__ tgB,
                                      int tx0, int ty0, int tid, float* sE) {
    // ---- pass 1: target edge magnitude into LDS (frame 34 x 136) ----
    for (int i = tid; i < EDGE_TASKS; i += NT) {
        int fr = i / 17;
        int p  = i - fr * 17;          // 0..16
        int gy  = ty0 - 1 + fr;
        int gxb = tx0 - 4 + 8 * p;     // gx of first edge col in this pair
        float a[10], b[10], c[10], e[8];
        loadrow<G>(a, tgB, gy - 1, gxb);
        loadrow<G>(b, tgB, gy,     gxb);
        loadrow<G>(c, tgB, gy + 1, gxb);
        sobel8(a, b, c, e);
        float4* dst = (float4*)&sE[fr * FRW + 8 * p];
        dst[0] = make_float4(e[0], e[1], e[2], e[3]);
        dst[1] = make_float4(e[4], e[5], e[6], e[7]);
    }
    __syncthreads();

    // ---- pass 2: pred edge (direct from global) + maxpool(sE) + loss ----
    float lsum = 0.f;
    #pragma unroll
    for (int it = 0; it < 2; ++it) {
        int t = tid + it * NT;         // 0..511
        int r = t >> 4;                // 0..31
        int p = t & 15;                // 0..15
        int gy  = ty0 + r;
        int gxb = tx0 + 8 * p;
        float a[10], b[10], c[10], pe[8];
        loadrow<G>(a, inB, gy - 1, gxb);
        loadrow<G>(b, inB, gy,     gxb);
        loadrow<G>(c, inB, gy + 1, gxb);
        sobel8(a, b, c, pe);

        float e0[10], e1[10], e2[10];
        ldsrow(e0, sE, r,     8 * p);
        ldsrow(e1, sE, r + 1, 8 * p);
        ldsrow(e2, sE, r + 2, 8 * p);
        #pragma unroll
        for (int k = 0; k < 10; ++k) e0[k] = fmaxf(fmaxf(e0[k], e1[k]), e2[k]);
        #pragma unroll
        for (int j = 0; j < 8; ++j) {
            float m = fmaxf(fmaxf(e0[j], e0[j + 1]), e0[j + 2]);
            float d = m * (pe[j] - 1.f);   // pe*te - te == te*(pe-1)
            lsum += d * d;
        }
    }
    return lsum;
}

__global__ __launch_bounds__(NT) void edge_loss_main(
    const float* __restrict__ inp, const float* __restrict__ tgt,
    double* __restrict__ acc) {
    __shared__ float sE[FRH * FRW];    // 18,496 B
    const int b   = blockIdx.z;
    const int ty0 = blockIdx.y * TY;
    const int tx0 = blockIdx.x * TX;
    const float* inB = inp + (size_t)b * (H * W);
    const float* tgB = tgt + (size_t)b * (H * W);
    const int tid = threadIdx.x;

    const bool g = (blockIdx.x == 0) | (blockIdx.x == GX - 1) |
                   (blockIdx.y == 0) | (blockIdx.y == GY - 1);
    float lsum = g ? body<true>(inB, tgB, tx0, ty0, tid, sE)
                   : body<false>(inB, tgB, tx0, ty0, tid, sE);

    // ---- reduce: wave64 shuffle -> LDS -> one double atomicAdd per block ----
    #pragma unroll
    for (int off = 32; off > 0; off >>= 1)
        lsum += __shfl_down(lsum, off);
    __shared__ float wsum[NT / 64];
    const int wave = tid >> 6, lane = tid & 63;
    if (lane == 0) wsum[wave] = lsum;
    __syncthreads();
    if (tid == 0) {
        float bsum = 0.f;
        #pragma unroll
        for (int w2 = 0; w2 < NT / 64; ++w2) bsum += wsum[w2];
        atomicAdd(acc, (double)bsum);
    }
}

__global__ void edge_loss_finalize(const double* __restrict__ acc,
                                   float* __restrict__ out) {
    out[0] = (float)(acc[0] / (double)((size_t)BATCH * H * W));
}

extern "C" void kernel_launch(void* const* d_in, const int* in_sizes, int n_in,
                              void* d_out, int out_size, void* d_ws, size_t ws_size,
                              hipStream_t stream) {
    const float* inputs  = (const float*)d_in[0];
    const float* targets = (const float*)d_in[1];
    float* out  = (float*)d_out;
    double* acc = (double*)d_ws;

    hipMemsetAsync(acc, 0, sizeof(double), stream);
    dim3 grid(GX, GY, BATCH);
    edge_loss_main<<<grid, NT, 0, stream>>>(inputs, targets, acc);
    edge_loss_finalize<<<1, 1, 0, stream>>>(acc, out);
}

// Round 3
// 68.535 us; speedup vs baseline: 2.1231x; 1.4964x over previous
//
#include <hip/hip_runtime.h>

#define H 1024
#define W 1024
#define BATCH 16
#define SW 8            // output cols per thread strip
#define SH 8            // output rows per thread strip
#define BCX 16          // col-strips per block
#define BRY 16          // row-strips per block
#define NT (BCX * BRY)  // 256 threads
#define TILE_X (SW * BCX)   // 128
#define TILE_Y (SH * BRY)   // 128
#define GXB (W / TILE_X)    // 8
#define GYB (H / TILE_Y)    // 8

// Load 16 floats: cols [gxb-4, gxb+12) of row gy. Tile origins are 8-aligned
// and W%4==0, so every float4 is entirely in- or entirely out-of-bounds.
template<bool GC, bool GR>
__device__ __forceinline__ void load16(float t[16], const float* __restrict__ img,
                                       int gy, int gxb) {
    bool rowok = true;
    if (GR) rowok = ((unsigned)gy < H);
    const float* row = img + (size_t)gy * W;
    #pragma unroll
    for (int q = 0; q < 4; ++q) {
        int gx = gxb - 4 + 4 * q;
        bool ok = rowok;
        if (GC) ok = ok && ((unsigned)gx <= (unsigned)(W - 4));
        float4 v = make_float4(0.f, 0.f, 0.f, 0.f);
        if (!GC && !GR) v = *(const float4*)(row + gx);
        else if (ok)    v = *(const float4*)(row + gx);
        t[4 * q + 0] = v.x; t[4 * q + 1] = v.y;
        t[4 * q + 2] = v.z; t[4 * q + 3] = v.w;
    }
}

// Squared Sobel magnitude row: 3 raw rows of 12 (col idx 0 <-> gxb-2) ->
// 10 edge^2 values (edge col idx j <-> gxb-1+j). No sqrt (maxpool commutes).
__device__ __forceinline__ void edge2_row(const float a[12], const float b[12],
                                          const float c[12], float e2[10]) {
    float t2[12], dz[12];
    #pragma unroll
    for (int k = 0; k < 12; ++k) {
        t2[k] = fmaf(2.f, b[k], a[k] + c[k]);
        dz[k] = c[k] - a[k];
    }
    #pragma unroll
    for (int j = 0; j < 10; ++j) {
        float gxv = t2[j + 2] - t2[j];
        float gyv = fmaf(2.f, dz[j + 1], dz[j]) + dz[j + 2];
        e2[j] = fmaf(gyv, gyv, gxv * gxv);
    }
}

// Sobel magnitude row: 3 raw rows of 10 (col idx 0 <-> gxb-1) -> 8 mags.
__device__ __forceinline__ void sobel_row10(const float a[10], const float b[10],
                                            const float c[10], float pe[8]) {
    float t2[10], dz[10];
    #pragma unroll
    for (int k = 0; k < 10; ++k) {
        t2[k] = fmaf(2.f, b[k], a[k] + c[k]);
        dz[k] = c[k] - a[k];
    }
    #pragma unroll
    for (int j = 0; j < 8; ++j) {
        float gxv = t2[j + 2] - t2[j];
        float gyv = fmaf(2.f, dz[j + 1], dz[j]) + dz[j + 2];
        pe[j] = sqrtf(fmaf(gyv, gyv, gxv * gxv));
    }
}

template<bool GC, bool GR>
__device__ __forceinline__ float strip(const float* __restrict__ pIn,
                                       const float* __restrict__ pTg,
                                       int tx0, int ty0) {
    const bool cz0 = GC && (tx0 == 0);          // edge col gxb-1 is OOB
    const bool czL = GC && (tx0 == W - SW);     // edge col gxb+8 is OOB
    float t[16];
    float tgA[12], tgB[12], tgC[12];            // rolling raw target rows
    float ia[10], ib[10], ic[10];               // rolling raw input rows
    float e2p[10], e2c[10], e2n[10];            // rolling squared edge rows

    // ---- prologue: e2p = edge^2(row ty0-1), e2c = edge^2(row ty0) ----
    float r0[12], r1[12];
    load16<GC, GR>(t, pTg, ty0 - 2, tx0);
    #pragma unroll
    for (int k = 0; k < 12; ++k) r0[k] = t[k + 2];
    load16<GC, GR>(t, pTg, ty0 - 1, tx0);
    #pragma unroll
    for (int k = 0; k < 12; ++k) r1[k] = t[k + 2];
    load16<GC, GR>(t, pTg, ty0, tx0);
    #pragma unroll
    for (int k = 0; k < 12; ++k) tgA[k] = t[k + 2];
    edge2_row(r0, r1, tgA, e2p);
    load16<GC, GR>(t, pTg, ty0 + 1, tx0);
    #pragma unroll
    for (int k = 0; k < 12; ++k) tgB[k] = t[k + 2];
    edge2_row(r1, tgA, tgB, e2c);
    if (GR && ty0 == 0) {                        // edge row -1 invalid
        #pragma unroll
        for (int j = 0; j < 10; ++j) e2p[j] = 0.f;
    }
    if (GC) {
        if (cz0) { e2p[0] = 0.f; e2c[0] = 0.f; }
        if (czL) { e2p[9] = 0.f; e2c[9] = 0.f; }
    }
    load16<GC, GR>(t, pIn, ty0 - 1, tx0);
    #pragma unroll
    for (int k = 0; k < 10; ++k) ia[k] = t[k + 3];
    load16<GC, GR>(t, pIn, ty0, tx0);
    #pragma unroll
    for (int k = 0; k < 10; ++k) ib[k] = t[k + 3];

    // ---- main: one output row (8 px) per iteration ----
    float lsum = 0.f;
    #pragma unroll
    for (int r = 0; r < SH; ++r) {
        const int gy = ty0 + r;
        load16<GC, GR>(t, pTg, gy + 2, tx0);
        #pragma unroll
        for (int k = 0; k < 12; ++k) tgC[k] = t[k + 2];
        edge2_row(tgA, tgB, tgC, e2n);           // edge^2 row gy+1
        if (GR && (gy + 1 >= H)) {
            #pragma unroll
            for (int j = 0; j < 10; ++j) e2n[j] = 0.f;
        }
        if (GC) {
            if (cz0) e2n[0] = 0.f;
            if (czL) e2n[9] = 0.f;
        }
        load16<GC, GR>(t, pIn, gy + 1, tx0);
        #pragma unroll
        for (int k = 0; k < 10; ++k) ic[k] = t[k + 3];
        float pe[8];
        sobel_row10(ia, ib, ic, pe);             // pred edge row gy

        float m3[10];
        #pragma unroll
        for (int j = 0; j < 10; ++j)
            m3[j] = fmaxf(fmaxf(e2p[j], e2c[j]), e2n[j]);
        #pragma unroll
        for (int j = 0; j < 8; ++j) {
            float mp = fmaxf(fmaxf(m3[j], m3[j + 1]), m3[j + 2]);
            float d = pe[j] - 1.f;               // loss = maxpool(e^2)*(pe-1)^2
            lsum = fmaf(mp * d, d, lsum);
        }
        #pragma unroll
        for (int k = 0; k < 12; ++k) { tgA[k] = tgB[k]; tgB[k] = tgC[k]; }
        #pragma unroll
        for (int k = 0; k < 10; ++k) { ia[k] = ib[k]; ib[k] = ic[k]; }
        #pragma unroll
        for (int j = 0; j < 10; ++j) { e2p[j] = e2c[j]; e2c[j] = e2n[j]; }
    }
    return lsum;
}

__global__ __launch_bounds__(NT) void edge_loss_main(
    const float* __restrict__ inp, const float* __restrict__ tgt,
    double* __restrict__ acc) {
    const int b   = blockIdx.z;
    const float* pIn = inp + (size_t)b * (H * W);
    const float* pTg = tgt + (size_t)b * (H * W);
    const int tid = threadIdx.x;
    const int csl = tid & (BCX - 1);
    const int rsl = tid >> 4;
    const int tx0 = blockIdx.x * TILE_X + csl * SW;
    const int ty0 = blockIdx.y * TILE_Y + rsl * SH;

    const bool gc = (blockIdx.x == 0) | (blockIdx.x == GXB - 1);
    const bool gr = (blockIdx.y == 0) | (blockIdx.y == GYB - 1);
    float lsum;
    if (gc) lsum = gr ? strip<true,  true >(pIn, pTg, tx0, ty0)
                      : strip<true,  false>(pIn, pTg, tx0, ty0);
    else    lsum = gr ? strip<false, true >(pIn, pTg, tx0, ty0)
                      : strip<false, false>(pIn, pTg, tx0, ty0);

    // ---- reduce: wave64 shuffle -> LDS -> one double atomicAdd per block ----
    #pragma unroll
    for (int off = 32; off > 0; off >>= 1)
        lsum += __shfl_down(lsum, off);
    __shared__ float wsum[NT / 64];
    const int wave = tid >> 6, lane = tid & 63;
    if (lane == 0) wsum[wave] = lsum;
    __syncthreads();
    if (tid == 0) {
        float bsum = 0.f;
        #pragma unroll
        for (int w2 = 0; w2 < NT / 64; ++w2) bsum += wsum[w2];
        atomicAdd(acc, (double)bsum);
    }
}

__global__ void edge_loss_finalize(const double* __restrict__ acc,
                                   float* __restrict__ out) {
    out[0] = (float)(acc[0] / (double)((size_t)BATCH * H * W));
}

extern "C" void kernel_launch(void* const* d_in, const int* in_sizes, int n_in,
                              void* d_out, int out_size, void* d_ws, size_t ws_size,
                              hipStream_t stream) {
    const float* inputs  = (const float*)d_in[0];
    const float* targets = (const float*)d_in[1];
    float* out  = (float*)d_out;
    double* acc = (double*)d_ws;

    hipMemsetAsync(acc, 0, sizeof(double), stream);
    dim3 grid(GXB, GYB, BATCH);
    edge_loss_main<<<grid, NT, 0, stream>>>(inputs, targets, acc);
    edge_loss_finalize<<<1, 1, 0, stream>>>(acc, out);
}